// Round 2
// baseline (2093.035 us; speedup 1.0000x reference)
//
#include <hip/hip_runtime.h>
#include <hip/hip_fp16.h>

typedef unsigned short us;
using short8 = __attribute__((ext_vector_type(8))) short;
using f32x4  = __attribute__((ext_vector_type(4))) float;
using u32x4  = __attribute__((ext_vector_type(4))) unsigned int;

#define B_  4
#define T_  2048
#define C_  2048
#define FF_ 8192
#define M_  (B_*T_)
#define NCH 16
#define LCH (T_/NCH)
#define EPS_WKV 1e-8f

// ---------- helpers ----------
__device__ __forceinline__ us f2bf(float f) {
  union { float f; unsigned u; } v; v.f = f;
  return (us)((v.u + 0x7fffu + ((v.u >> 16) & 1u)) >> 16);
}

// pack two fp32 -> two bf16 (round-half-up via +0x8000, then byte-perm)
__device__ __forceinline__ unsigned pack2bf(float a, float b) {
  union { float f; unsigned u; } x, y; x.f = a; y.f = b;
  return __builtin_amdgcn_perm(y.u + 0x8000u, x.u + 0x8000u, 0x07060302u);
}

__device__ __forceinline__ void gload_lds16(const void* g, void* l) {
  __builtin_amdgcn_global_load_lds((__attribute__((address_space(1))) void*)(void*)g,
                                   (__attribute__((address_space(3))) void*)l, 16, 0, 0);
}

// ---------- LayerNorm: fp32 in -> bf16 out (+ optional fp32 state row) ----------
template<bool WS>
__global__ __launch_bounds__(256)
void ln_kern(const float* __restrict__ x, const float* __restrict__ g,
             const float* __restrict__ bi, us* __restrict__ y,
             float* __restrict__ state)
{
  const int row = blockIdx.x;
  const int tid = threadIdx.x;
  const float* xr = x + (size_t)row * C_;
  const float4 v0 = ((const float4*)xr)[tid];
  const float4 v1 = ((const float4*)xr)[tid + 256];
  float s  = v0.x + v0.y + v0.z + v0.w + v1.x + v1.y + v1.z + v1.w;
  float sq = v0.x*v0.x + v0.y*v0.y + v0.z*v0.z + v0.w*v0.w
           + v1.x*v1.x + v1.y*v1.y + v1.z*v1.z + v1.w*v1.w;
  #pragma unroll
  for (int o = 32; o > 0; o >>= 1) { s += __shfl_down(s, o, 64); sq += __shfl_down(sq, o, 64); }
  __shared__ float ws_[4], wq_[4];
  if ((tid & 63) == 0) { ws_[tid >> 6] = s; wq_[tid >> 6] = sq; }
  __syncthreads();
  s  = ws_[0] + ws_[1] + ws_[2] + ws_[3];
  sq = wq_[0] + wq_[1] + wq_[2] + wq_[3];
  const float mean = s * (1.f / C_);
  const float rstd = rsqrtf(sq * (1.f / C_) - mean * mean + 1e-5f);
  const float4 g0 = ((const float4*)g)[tid],  g1 = ((const float4*)g)[tid + 256];
  const float4 b0 = ((const float4*)bi)[tid], b1 = ((const float4*)bi)[tid + 256];
  const float o0x = (v0.x - mean) * rstd * g0.x + b0.x;
  const float o0y = (v0.y - mean) * rstd * g0.y + b0.y;
  const float o0z = (v0.z - mean) * rstd * g0.z + b0.z;
  const float o0w = (v0.w - mean) * rstd * g0.w + b0.w;
  const float o1x = (v1.x - mean) * rstd * g1.x + b1.x;
  const float o1y = (v1.y - mean) * rstd * g1.y + b1.y;
  const float o1z = (v1.z - mean) * rstd * g1.z + b1.z;
  const float o1w = (v1.w - mean) * rstd * g1.w + b1.w;
  ushort4 p0; p0.x = f2bf(o0x); p0.y = f2bf(o0y); p0.z = f2bf(o0z); p0.w = f2bf(o0w);
  ushort4 p1; p1.x = f2bf(o1x); p1.y = f2bf(o1y); p1.z = f2bf(o1z); p1.w = f2bf(o1w);
  ((ushort4*)(y + (size_t)row * C_))[tid]       = p0;
  ((ushort4*)(y + (size_t)row * C_))[tid + 256] = p1;
  if (WS && ((row & (T_ - 1)) == (T_ - 2))) {
    float* st = state + (size_t)(row >> 11) * C_;
    const int c0 = tid * 4;
    st[c0 + 0] = o0x; st[c0 + 1] = o0y; st[c0 + 2] = o0z; st[c0 + 3] = o0w;
    st[c0 + 1024 + 0] = o1x; st[c0 + 1024 + 1] = o1y;
    st[c0 + 1024 + 2] = o1z; st[c0 + 1024 + 3] = o1w;
  }
}

// ---------- NT GEMM: out[m,n] = sum_k A[m,k] * Bw[n,k]
// A: bf16, row stride C_ (2048). Bw: fp32, row stride ldb (converted to bf16 in staging).
// K = C_ = 2048 for every GEMM in this problem. Output row stride C_.
// MODE 0: fp16 store   MODE 1: relu(acc)^2 -> bf16   MODE 2: sigmoid -> fp16
// MODE 3: fout += crv*acc   MODE 4: fp32 store
template<int MODE>
__global__ __launch_bounds__(256)
void gemm_nt(const us* __restrict__ A, const float* __restrict__ Bw, int ldb,
             void* __restrict__ out0, const __half* __restrict__ crv,
             float* __restrict__ fout)
{
  __shared__ __align__(16) us sA[4096];
  __shared__ __align__(16) us sB[4096];
  const int tid  = threadIdx.x;
  const int wave = tid >> 6, lane = tid & 63;
  const int quad = lane >> 4, l16 = lane & 15;
  const int wm = wave & 1, wn = wave >> 1;
  const size_t m0 = (size_t)blockIdx.y * 128, n0 = (size_t)blockIdx.x * 128;

  f32x4 acc[4][4];
  #pragma unroll
  for (int i = 0; i < 4; i++)
    #pragma unroll
    for (int j = 0; j < 4; j++)
      acc[i][j] = (f32x4){0.f, 0.f, 0.f, 0.f};

  const us* gA  = A + (m0 + (size_t)(tid >> 2)) * C_ + (size_t)((tid & 3) * 8);
  const us* gA2 = gA + (size_t)64 * C_;
  const float* gB  = Bw + (n0 + (size_t)(tid >> 2)) * (size_t)ldb + (size_t)((tid & 3) * 8);
  const float* gB2 = gB + (size_t)64 * (size_t)ldb;
  us* lA  = &sA[wave * 512];
  us* lA2 = &sA[2048 + wave * 512];
  us* wB  = &sB[(tid >> 2) * 32 + (tid & 3) * 8];
  us* wB2 = wB + 2048;
  const us* pA = &sA[(wm * 64 + l16) * 32 + quad * 8];
  const us* pB = &sB[(wn * 64 + l16) * 32 + quad * 8];

  for (int kt = 0; kt < C_; kt += 32) {
    gload_lds16(gA,  lA);
    gload_lds16(gA2, lA2);
    const float4 b0 = *(const float4*)gB;
    const float4 b1 = *(const float4*)(gB + 4);
    const float4 b2 = *(const float4*)gB2;
    const float4 b3 = *(const float4*)(gB2 + 4);
    gA += 32; gA2 += 32; gB += 32; gB2 += 32;
    u32x4 p0 = { pack2bf(b0.x,b0.y), pack2bf(b0.z,b0.w), pack2bf(b1.x,b1.y), pack2bf(b1.z,b1.w) };
    u32x4 p1 = { pack2bf(b2.x,b2.y), pack2bf(b2.z,b2.w), pack2bf(b3.x,b3.y), pack2bf(b3.z,b3.w) };
    *(u32x4*)wB  = p0;
    *(u32x4*)wB2 = p1;
    __syncthreads();
    short8 af[4], bf[4];
    #pragma unroll
    for (int i = 0; i < 4; i++) af[i] = *(const short8*)(pA + i * 512);
    #pragma unroll
    for (int i = 0; i < 4; i++) bf[i] = *(const short8*)(pB + i * 512);
    #pragma unroll
    for (int im = 0; im < 4; im++)
      #pragma unroll
      for (int in2 = 0; in2 < 4; in2++)
        acc[im][in2] = __builtin_amdgcn_mfma_f32_16x16x32_bf16(af[im], bf[in2], acc[im][in2], 0, 0, 0);
    __syncthreads();
  }

  #pragma unroll
  for (int im = 0; im < 4; im++) {
    const size_t rbase = m0 + (size_t)(wm * 64 + im * 16 + quad * 4);
    #pragma unroll
    for (int j = 0; j < 4; j++) {
      const size_t rowoff = (rbase + j) * C_;
      #pragma unroll
      for (int in2 = 0; in2 < 4; in2++) {
        const size_t idx = rowoff + n0 + (size_t)(wn * 64 + in2 * 16 + l16);
        const float v = acc[im][in2][j];
        if (MODE == 0) {
          ((__half*)out0)[idx] = __float2half(v);
        } else if (MODE == 1) {
          const float t = v > 0.f ? v : 0.f;
          ((us*)out0)[idx] = f2bf(t * t);
        } else if (MODE == 2) {
          ((__half*)out0)[idx] = __float2half(1.f / (1.f + expf(-v)));
        } else if (MODE == 3) {
          fout[idx] += (float)crv[idx] * v;
        } else {
          ((float*)out0)[idx] = v;
        }
      }
    }
  }
}

// ---------- WKV chunked scan ----------
__global__ __launch_bounds__(256)
void wkv_pass1(const __half* __restrict__ Kh, const __half* __restrict__ Vh,
               const float* __restrict__ tdec, float* __restrict__ chA, float* __restrict__ chB)
{
  const int idx = blockIdx.x * 256 + threadIdx.x;       // over B*NCH*C
  const int c = idx & (C_ - 1);
  const int chunk = (idx >> 11) & (NCH - 1);
  const int b = idx >> 15;
  const float d = expf(-expf(tdec[c]));
  const size_t base = ((size_t)b * T_) * C_ + c;
  float a = 0.f, bb = 0.f;
  const int t0 = chunk * LCH;
  int t = t0;
  if (chunk == 0) { bb = 1.f; t = 1; }                  // t=0: ek=exp(0)=1, v=0
  const int tend = t0 + LCH;
  #pragma unroll 4
  for (; t < tend; ++t) {
    const size_t off = base + (size_t)(t - 1) * C_;
    const float ek = expf((float)Kh[off]);
    const float vv = (float)Vh[off];
    a  = d * a  + ek * vv;
    bb = d * bb + ek;
  }
  chA[idx] = a; chB[idx] = bb;
}

__global__ __launch_bounds__(256)
void wkv_pass2(const float* __restrict__ tdec, float* __restrict__ chA, float* __restrict__ chB)
{
  const int idx = blockIdx.x * 256 + threadIdx.x;       // over B*C
  const int c = idx & (C_ - 1);
  const int b = idx >> 11;
  const float dL = expf(-expf(tdec[c]) * (float)LCH);
  float a = 0.f, bb = 0.f;
  #pragma unroll
  for (int ch = 0; ch < NCH; ++ch) {
    const int s = (b * NCH + ch) * C_ + c;
    const float la = chA[s], lb = chB[s];
    chA[s] = a; chB[s] = bb;                            // incoming state for chunk
    a  = dL * a  + la;
    bb = dL * bb + lb;
  }
}

// r is pre-stored fp32 in outx; read it, overwrite in place with x + r*wkv
__global__ __launch_bounds__(256)
void wkv_pass3(const __half* __restrict__ Kh, const __half* __restrict__ Vh,
               const float* __restrict__ xin, const float* __restrict__ tdec,
               const float* __restrict__ chA, const float* __restrict__ chB,
               float* __restrict__ outx)
{
  const int idx = blockIdx.x * 256 + threadIdx.x;       // over B*NCH*C
  const int c = idx & (C_ - 1);
  const int chunk = (idx >> 11) & (NCH - 1);
  const int b = idx >> 15;
  const float d = expf(-expf(tdec[c]));
  const size_t base = ((size_t)b * T_) * C_ + c;
  float a = chA[idx], bb = chB[idx];
  const int t0 = chunk * LCH;
  int t = t0;
  if (chunk == 0) {
    a = d * a;                                          // + 1*0
    bb = d * bb + 1.f;
    const float wkv = a / (bb + EPS_WKV);
    const float r = outx[base];
    outx[base] = xin[base] + r * wkv;
    t = 1;
  }
  const int tend = t0 + LCH;
  #pragma unroll 4
  for (; t < tend; ++t) {
    const size_t offp = base + (size_t)(t - 1) * C_;
    const size_t off  = base + (size_t)t * C_;
    const float ek = expf((float)Kh[offp]);
    const float vv = (float)Vh[offp];
    a  = d * a  + ek * vv;
    bb = d * bb + ek;
    const float wkv = a / (bb + EPS_WKV);
    const float r = outx[off];
    outx[off] = xin[off] + r * wkv;
  }
}

// ---------- launch ----------
extern "C" void kernel_launch(void* const* d_in, const int* in_sizes, int n_in,
                              void* d_out, int out_size, void* d_ws, size_t ws_size,
                              hipStream_t stream)
{
  const float* x    = (const float*)d_in[0];
  const float* ln1g = (const float*)d_in[1];
  const float* ln1b = (const float*)d_in[2];
  const float* tdec = (const float*)d_in[3];
  const float* Wk   = (const float*)d_in[4];
  const float* Wv   = (const float*)d_in[5];
  const float* Wr   = (const float*)d_in[6];
  const float* ln2g = (const float*)d_in[7];
  const float* ln2b = (const float*)d_in[8];
  const float* Wck  = (const float*)d_in[9];
  const float* Wcv  = (const float*)d_in[10];
  const float* Wcr  = (const float*)d_in[11];

  // 97 MiB workspace layout (aliases exploit phase-disjoint lifetimes):
  //  [0,32Mi)   xln  bf16 M*C   -> later ck_chunk bf16 M*2048
  //  [32,64Mi)  Kb   fp16 M*C   -> later x2 bf16 M*C
  //  [64,96Mi)  Vb   fp16 M*C   -> later crb fp16 M*C
  //  [96Mi,+1Mi) chA, chB fp32 B*NCH*C each
  char* ws = (char*)d_ws;
  us*     xln = (us*)(ws);
  __half* Kb  = (__half*)(ws + (32ull << 20));
  __half* Vb  = (__half*)(ws + (64ull << 20));
  float*  chA = (float*)(ws + (96ull << 20));
  float*  chB = (float*)(ws + (96ull << 20) + 524288ull);
  us*     x2  = (us*)Kb;
  __half* crb = (__half*)Vb;
  us*     ckc = (us*)xln;

  float* outx = (float*)d_out;
  float* outs = outx + (size_t)M_ * C_;

  const dim3 blk(256);
  const dim3 gC(C_ / 128, M_ / 128);   // (16, 64) — every GEMM here is 8192x2048xK2048

  // LN1 (+ state = xln row T-2 per batch)
  ln_kern<true><<<M_, blk, 0, stream>>>(x, ln1g, ln1b, xln, outs);

  // k, v (fp16), r (fp32, straight into d_out)
  gemm_nt<0><<<gC, blk, 0, stream>>>(xln, Wk, C_, (void*)Kb, nullptr, nullptr);
  gemm_nt<0><<<gC, blk, 0, stream>>>(xln, Wv, C_, (void*)Vb, nullptr, nullptr);
  gemm_nt<4><<<gC, blk, 0, stream>>>(xln, Wr, C_, (void*)outx, nullptr, nullptr);

  // chunked WKV scan; pass3 rewrites outx in place: x + r*wkv
  wkv_pass1<<<(B_ * NCH * C_) / 256, blk, 0, stream>>>(Kb, Vb, tdec, chA, chB);
  wkv_pass2<<<(B_ * C_) / 256,       blk, 0, stream>>>(tdec, chA, chB);
  wkv_pass3<<<(B_ * NCH * C_) / 256, blk, 0, stream>>>(Kb, Vb, x, tdec, chA, chB, outx);

  // LN2 -> x2 (bf16)
  ln_kern<false><<<M_, blk, 0, stream>>>(outx, ln2g, ln2b, x2, nullptr);

  // cr = sigmoid(x2 @ Wcr^T) -> fp16
  gemm_nt<2><<<gC, blk, 0, stream>>>(x2, Wcr, C_, (void*)crb, nullptr, nullptr);

  // FFN chunked over FF: ck_chunk = relu(x2 @ Wck_f^T)^2 ; out += cr * (ck_chunk @ Wcv_f^T)
  for (int f0 = 0; f0 < FF_; f0 += 2048) {
    gemm_nt<1><<<gC, blk, 0, stream>>>(x2, Wck + (size_t)f0 * C_, C_, (void*)ckc, nullptr, nullptr);
    gemm_nt<3><<<gC, blk, 0, stream>>>(ckc, Wcv + f0, FF_, nullptr, crb, outx);
  }
}

// Round 3
// 1621.768 us; speedup vs baseline: 1.2906x; 1.2906x over previous
//
#include <hip/hip_runtime.h>
#include <hip/hip_fp16.h>

typedef unsigned short us;
using short8 = __attribute__((ext_vector_type(8))) short;
using f32x4  = __attribute__((ext_vector_type(4))) float;

#define B_  4
#define T_  2048
#define C_  2048
#define FF_ 8192
#define M_  (B_*T_)
#define NCH 16
#define LCH (T_/NCH)
#define EPS_WKV 1e-8f

// ---------- helpers ----------
__device__ __forceinline__ us f2bf(float f) {
  union { float f; unsigned u; } v; v.f = f;
  return (us)((v.u + 0x7fffu + ((v.u >> 16) & 1u)) >> 16);
}

__device__ __forceinline__ void gload_lds16(const void* g, void* l) {
  __builtin_amdgcn_global_load_lds((__attribute__((address_space(1))) void*)(void*)g,
                                   (__attribute__((address_space(3))) void*)l, 16, 0, 0);
}

// ---------- fp32 -> bf16, contiguous (1024 elems / block) ----------
__global__ __launch_bounds__(256)
void cvt_bf16(const float* __restrict__ s, us* __restrict__ d) {
  const int i = (blockIdx.x * 256 + threadIdx.x) * 4;
  const float4 v = *(const float4*)(s + i);
  ushort4 o; o.x = f2bf(v.x); o.y = f2bf(v.y); o.z = f2bf(v.z); o.w = f2bf(v.w);
  *(ushort4*)(d + i) = o;
}

// ---------- fp32 -> bf16, strided source rows (for Wcv column slab) ----------
// grid (2, 2048): 2048-row block; src row stride srs, dst row stride 2048
__global__ __launch_bounds__(256)
void cvt_bf16_str(const float* __restrict__ s, us* __restrict__ d, int srs) {
  const int row = blockIdx.y;
  const int col = (blockIdx.x * 256 + threadIdx.x) * 4;
  const float4 v = *(const float4*)(s + (size_t)row * srs + col);
  ushort4 o; o.x = f2bf(v.x); o.y = f2bf(v.y); o.z = f2bf(v.z); o.w = f2bf(v.w);
  *(ushort4*)(d + (size_t)row * 2048 + col) = o;
}

// ---------- LayerNorm: fp32 in -> bf16 out (+ optional fp32 state row) ----------
template<bool WS>
__global__ __launch_bounds__(256)
void ln_kern(const float* __restrict__ x, const float* __restrict__ g,
             const float* __restrict__ bi, us* __restrict__ y,
             float* __restrict__ state)
{
  const int row = blockIdx.x;
  const int tid = threadIdx.x;
  const float* xr = x + (size_t)row * C_;
  const float4 v0 = ((const float4*)xr)[tid];
  const float4 v1 = ((const float4*)xr)[tid + 256];
  float s  = v0.x + v0.y + v0.z + v0.w + v1.x + v1.y + v1.z + v1.w;
  float sq = v0.x*v0.x + v0.y*v0.y + v0.z*v0.z + v0.w*v0.w
           + v1.x*v1.x + v1.y*v1.y + v1.z*v1.z + v1.w*v1.w;
  #pragma unroll
  for (int o = 32; o > 0; o >>= 1) { s += __shfl_down(s, o, 64); sq += __shfl_down(sq, o, 64); }
  __shared__ float ws_[4], wq_[4];
  if ((tid & 63) == 0) { ws_[tid >> 6] = s; wq_[tid >> 6] = sq; }
  __syncthreads();
  s  = ws_[0] + ws_[1] + ws_[2] + ws_[3];
  sq = wq_[0] + wq_[1] + wq_[2] + wq_[3];
  const float mean = s * (1.f / C_);
  const float rstd = rsqrtf(sq * (1.f / C_) - mean * mean + 1e-5f);
  const float4 g0 = ((const float4*)g)[tid],  g1 = ((const float4*)g)[tid + 256];
  const float4 b0 = ((const float4*)bi)[tid], b1 = ((const float4*)bi)[tid + 256];
  const float o0x = (v0.x - mean) * rstd * g0.x + b0.x;
  const float o0y = (v0.y - mean) * rstd * g0.y + b0.y;
  const float o0z = (v0.z - mean) * rstd * g0.z + b0.z;
  const float o0w = (v0.w - mean) * rstd * g0.w + b0.w;
  const float o1x = (v1.x - mean) * rstd * g1.x + b1.x;
  const float o1y = (v1.y - mean) * rstd * g1.y + b1.y;
  const float o1z = (v1.z - mean) * rstd * g1.z + b1.z;
  const float o1w = (v1.w - mean) * rstd * g1.w + b1.w;
  ushort4 p0; p0.x = f2bf(o0x); p0.y = f2bf(o0y); p0.z = f2bf(o0z); p0.w = f2bf(o0w);
  ushort4 p1; p1.x = f2bf(o1x); p1.y = f2bf(o1y); p1.z = f2bf(o1z); p1.w = f2bf(o1w);
  ((ushort4*)(y + (size_t)row * C_))[tid]       = p0;
  ((ushort4*)(y + (size_t)row * C_))[tid + 256] = p1;
  if (WS && ((row & (T_ - 1)) == (T_ - 2))) {
    float* st = state + (size_t)(row >> 11) * C_;
    const int c0 = tid * 4;
    st[c0 + 0] = o0x; st[c0 + 1] = o0y; st[c0 + 2] = o0z; st[c0 + 3] = o0w;
    st[c0 + 1024 + 0] = o1x; st[c0 + 1024 + 1] = o1y;
    st[c0 + 1024 + 2] = o1z; st[c0 + 1024 + 3] = o1w;
  }
}

// ---------- NT GEMM: out[m,n] = sum_k A[m,k] * Bw[n,k]
// A, Bw: bf16 row-major, row stride C_ (2048). K = C_ for every GEMM here.
// MODE 1: relu(acc)^2 -> bf16    MODE 2: sigmoid -> fp16
// MODE 3: fout += crv*acc        MODE 5: fused kvr split (k,v->fp16; r->fp32)
template<int MODE>
__global__ __launch_bounds__(256)
void gemm_nt(const us* __restrict__ A, const us* __restrict__ Bw,
             void* __restrict__ out0, void* __restrict__ out1, void* __restrict__ out2,
             const __half* __restrict__ crv, float* __restrict__ fout)
{
  __shared__ __align__(16) us sA[4096];
  __shared__ __align__(16) us sB[4096];
  const int tid  = threadIdx.x;
  const int wave = tid >> 6, lane = tid & 63;
  const int quad = lane >> 4, l16 = lane & 15;
  const int wm = wave & 1, wn = wave >> 1;
  const size_t m0 = (size_t)blockIdx.y * 128, n0 = (size_t)blockIdx.x * 128;

  f32x4 acc[4][4];
  #pragma unroll
  for (int i = 0; i < 4; i++)
    #pragma unroll
    for (int j = 0; j < 4; j++)
      acc[i][j] = (f32x4){0.f, 0.f, 0.f, 0.f};

  const us* gA  = A  + (m0 + (size_t)(tid >> 2)) * C_ + (size_t)((tid & 3) * 8);
  const us* gA2 = gA + (size_t)64 * C_;
  const us* gB  = Bw + (n0 + (size_t)(tid >> 2)) * C_ + (size_t)((tid & 3) * 8);
  const us* gB2 = gB + (size_t)64 * C_;
  us* lA  = &sA[wave * 512];
  us* lA2 = &sA[2048 + wave * 512];
  us* lB  = &sB[wave * 512];
  us* lB2 = &sB[2048 + wave * 512];
  const us* pA = &sA[(wm * 64 + l16) * 32 + quad * 8];
  const us* pB = &sB[(wn * 64 + l16) * 32 + quad * 8];

  for (int kt = 0; kt < C_; kt += 32) {
    gload_lds16(gA,  lA);
    gload_lds16(gA2, lA2);
    gload_lds16(gB,  lB);
    gload_lds16(gB2, lB2);
    gA += 32; gA2 += 32; gB += 32; gB2 += 32;
    __syncthreads();
    short8 af[4], bf[4];
    #pragma unroll
    for (int i = 0; i < 4; i++) af[i] = *(const short8*)(pA + i * 512);
    #pragma unroll
    for (int i = 0; i < 4; i++) bf[i] = *(const short8*)(pB + i * 512);
    #pragma unroll
    for (int im = 0; im < 4; im++)
      #pragma unroll
      for (int in2 = 0; in2 < 4; in2++)
        acc[im][in2] = __builtin_amdgcn_mfma_f32_16x16x32_bf16(af[im], bf[in2], acc[im][in2], 0, 0, 0);
    __syncthreads();
  }

  // which sub-matrix for the fused kvr GEMM (uniform per block: n0 in [0,6144))
  const int nb = (int)(n0 >> 11);            // 0=k, 1=v, 2=r
  const size_t ncol0 = n0 - ((size_t)nb << 11);

  #pragma unroll
  for (int im = 0; im < 4; im++) {
    const size_t rbase = m0 + (size_t)(wm * 64 + im * 16 + quad * 4);
    #pragma unroll
    for (int j = 0; j < 4; j++) {
      const size_t rowoff = (rbase + j) * C_;
      #pragma unroll
      for (int in2 = 0; in2 < 4; in2++) {
        const size_t nc = (size_t)(wn * 64 + in2 * 16 + l16);
        const float v = acc[im][in2][j];
        if (MODE == 1) {
          const float t = v > 0.f ? v : 0.f;
          ((us*)out0)[rowoff + n0 + nc] = f2bf(t * t);
        } else if (MODE == 2) {
          ((__half*)out0)[rowoff + n0 + nc] = __float2half(1.f / (1.f + expf(-v)));
        } else if (MODE == 3) {
          const size_t idx = rowoff + n0 + nc;
          fout[idx] += (float)crv[idx] * v;
        } else { // MODE 5: fused k,v,r
          const size_t idx = rowoff + ncol0 + nc;
          if (nb == 0)      ((__half*)out0)[idx] = __float2half(v);
          else if (nb == 1) ((__half*)out1)[idx] = __float2half(v);
          else              ((float*)out2)[idx]  = v;
        }
      }
    }
  }
}

// ---------- WKV chunked scan ----------
__global__ __launch_bounds__(256)
void wkv_pass1(const __half* __restrict__ Kh, const __half* __restrict__ Vh,
               const float* __restrict__ tdec, float* __restrict__ chA, float* __restrict__ chB)
{
  const int idx = blockIdx.x * 256 + threadIdx.x;       // over B*NCH*C
  const int c = idx & (C_ - 1);
  const int chunk = (idx >> 11) & (NCH - 1);
  const int b = idx >> 15;
  const float d = expf(-expf(tdec[c]));
  const size_t base = ((size_t)b * T_) * C_ + c;
  float a = 0.f, bb = 0.f;
  const int t0 = chunk * LCH;
  int t = t0;
  if (chunk == 0) { bb = 1.f; t = 1; }                  // t=0: ek=exp(0)=1, v=0
  const int tend = t0 + LCH;
  #pragma unroll 4
  for (; t < tend; ++t) {
    const size_t off = base + (size_t)(t - 1) * C_;
    const float ek = expf((float)Kh[off]);
    const float vv = (float)Vh[off];
    a  = d * a  + ek * vv;
    bb = d * bb + ek;
  }
  chA[idx] = a; chB[idx] = bb;
}

__global__ __launch_bounds__(256)
void wkv_pass2(const float* __restrict__ tdec, float* __restrict__ chA, float* __restrict__ chB)
{
  const int idx = blockIdx.x * 256 + threadIdx.x;       // over B*C
  const int c = idx & (C_ - 1);
  const int b = idx >> 11;
  const float dL = expf(-expf(tdec[c]) * (float)LCH);
  float a = 0.f, bb = 0.f;
  #pragma unroll
  for (int ch = 0; ch < NCH; ++ch) {
    const int s = (b * NCH + ch) * C_ + c;
    const float la = chA[s], lb = chB[s];
    chA[s] = a; chB[s] = bb;                            // incoming state for chunk
    a  = dL * a  + la;
    bb = dL * bb + lb;
  }
}

// r is pre-stored fp32 in outx; read it, overwrite in place with x + r*wkv
__global__ __launch_bounds__(256)
void wkv_pass3(const __half* __restrict__ Kh, const __half* __restrict__ Vh,
               const float* __restrict__ xin, const float* __restrict__ tdec,
               const float* __restrict__ chA, const float* __restrict__ chB,
               float* __restrict__ outx)
{
  const int idx = blockIdx.x * 256 + threadIdx.x;       // over B*NCH*C
  const int c = idx & (C_ - 1);
  const int chunk = (idx >> 11) & (NCH - 1);
  const int b = idx >> 15;
  const float d = expf(-expf(tdec[c]));
  const size_t base = ((size_t)b * T_) * C_ + c;
  float a = chA[idx], bb = chB[idx];
  const int t0 = chunk * LCH;
  int t = t0;
  if (chunk == 0) {
    a = d * a;                                          // + 1*0
    bb = d * bb + 1.f;
    const float wkv = a / (bb + EPS_WKV);
    const float r = outx[base];
    outx[base] = xin[base] + r * wkv;
    t = 1;
  }
  const int tend = t0 + LCH;
  #pragma unroll 4
  for (; t < tend; ++t) {
    const size_t offp = base + (size_t)(t - 1) * C_;
    const size_t off  = base + (size_t)t * C_;
    const float ek = expf((float)Kh[offp]);
    const float vv = (float)Vh[offp];
    a  = d * a  + ek * vv;
    bb = d * bb + ek;
    const float wkv = a / (bb + EPS_WKV);
    const float r = outx[off];
    outx[off] = xin[off] + r * wkv;
  }
}

// ---------- launch ----------
extern "C" void kernel_launch(void* const* d_in, const int* in_sizes, int n_in,
                              void* d_out, int out_size, void* d_ws, size_t ws_size,
                              hipStream_t stream)
{
  const float* x    = (const float*)d_in[0];
  const float* ln1g = (const float*)d_in[1];
  const float* ln1b = (const float*)d_in[2];
  const float* tdec = (const float*)d_in[3];
  const float* Wk   = (const float*)d_in[4];
  const float* Wv   = (const float*)d_in[5];
  const float* Wr   = (const float*)d_in[6];
  const float* ln2g = (const float*)d_in[7];
  const float* ln2b = (const float*)d_in[8];
  const float* Wck  = (const float*)d_in[9];
  const float* Wcv  = (const float*)d_in[10];
  const float* Wcr  = (const float*)d_in[11];

  // 145 MiB workspace (phase-disjoint aliases):
  //  [0,32Mi)    xln bf16 M*C          -> later ck_chunk bf16 M*2048
  //  [32,64Mi)   Kb fp16 M*C           -> later x2 bf16 M*C
  //  [64,96Mi)   Vb fp16 M*C           -> later crb fp16 M*C
  //  [96,97Mi)   chA, chB fp32 B*NCH*C
  //  [97,121Mi)  wkvr bf16 6144*2048 (Wk|Wv|Wr converted)
  //  [121,129Mi) wcrb bf16 2048*2048
  //  [129,137Mi) wckc bf16 2048*2048 (per-FF-slab)
  //  [137,145Mi) wcvc bf16 2048*2048 (per-FF-slab)
  char* ws = (char*)d_ws;
  us*     xln  = (us*)(ws);
  __half* Kb   = (__half*)(ws + (32ull  << 20));
  __half* Vb   = (__half*)(ws + (64ull  << 20));
  float*  chA  = (float*)(ws + (96ull << 20));
  float*  chB  = (float*)(ws + (96ull << 20) + 524288ull);
  us*     wkvr = (us*)(ws + (97ull  << 20));
  us*     wcrb = (us*)(ws + (121ull << 20));
  us*     wckc = (us*)(ws + (129ull << 20));
  us*     wcvc = (us*)(ws + (137ull << 20));
  us*     x2   = (us*)Kb;
  __half* crb  = (__half*)Vb;
  us*     ckc  = (us*)xln;

  float* outx = (float*)d_out;
  float* outs = outx + (size_t)M_ * C_;

  const dim3 blk(256);
  const dim3 gC(C_ / 128, M_ / 128);     // (16, 64)
  const dim3 gKVR(3 * C_ / 128, M_ / 128); // (48, 64)

  // convert k/v/r/cr weights to bf16 (contiguous, 4M elems each -> 4096 blocks)
  cvt_bf16<<<4096, blk, 0, stream>>>(Wk,  wkvr);
  cvt_bf16<<<4096, blk, 0, stream>>>(Wv,  wkvr + (size_t)C_ * C_);
  cvt_bf16<<<4096, blk, 0, stream>>>(Wr,  wkvr + 2 * (size_t)C_ * C_);
  cvt_bf16<<<4096, blk, 0, stream>>>(Wcr, wcrb);

  // LN1 (+ state = xln row T-2 per batch)
  ln_kern<true><<<M_, blk, 0, stream>>>(x, ln1g, ln1b, xln, outs);

  // fused k|v|r GEMM: N=6144; k,v -> fp16, r -> fp32 straight into d_out
  gemm_nt<5><<<gKVR, blk, 0, stream>>>(xln, wkvr, (void*)Kb, (void*)Vb, (void*)outx, nullptr, nullptr);

  // chunked WKV scan; pass3 rewrites outx in place: x + r*wkv
  wkv_pass1<<<(B_ * NCH * C_) / 256, blk, 0, stream>>>(Kb, Vb, tdec, chA, chB);
  wkv_pass2<<<(B_ * C_) / 256,       blk, 0, stream>>>(tdec, chA, chB);
  wkv_pass3<<<(B_ * NCH * C_) / 256, blk, 0, stream>>>(Kb, Vb, x, tdec, chA, chB, outx);

  // LN2 -> x2 (bf16)
  ln_kern<false><<<M_, blk, 0, stream>>>(outx, ln2g, ln2b, x2, nullptr);

  // cr = sigmoid(x2 @ Wcr^T) -> fp16
  gemm_nt<2><<<gC, blk, 0, stream>>>(x2, wcrb, (void*)crb, nullptr, nullptr, nullptr, nullptr);

  // FFN in 4 slabs of 2048: ck = relu(x2 @ Wck_f^T)^2 ; out += cr * (ck @ Wcv_f^T)
  for (int f0 = 0; f0 < FF_; f0 += 2048) {
    cvt_bf16<<<4096, blk, 0, stream>>>(Wck + (size_t)f0 * C_, wckc);
    gemm_nt<1><<<gC, blk, 0, stream>>>(x2, wckc, (void*)ckc, nullptr, nullptr, nullptr, nullptr);
    cvt_bf16_str<<<dim3(2, 2048), blk, 0, stream>>>(Wcv + f0, wcvc, FF_);
    gemm_nt<3><<<gC, blk, 0, stream>>>(ckc, wcvc, nullptr, nullptr, nullptr, crb, outx);
  }
}